// Round 9
// baseline (216.690 us; speedup 1.0000x reference)
//
#include <hip/hip_runtime.h>
#include <math.h>

// Problem constants
constexpr int Dm   = 1024;
constexpr int NH   = 16;
constexpr int HD   = 64;
constexpr int Bb   = 2;
constexpr int Tt   = 2048;
constexpr int MTOT = Bb * Tt;   // 4096
#define EPSF 1e-6f

typedef __attribute__((ext_vector_type(8))) short short8;   // 8 x bf16
typedef __attribute__((ext_vector_type(4))) float f32x4;    // MFMA acc (16x16)
typedef __attribute__((ext_vector_type(16))) float f32x16;  // MFMA acc (32x32)
typedef __attribute__((ext_vector_type(2))) float f32x2;    // packed fp32 pair

__device__ __forceinline__ ushort f2bf(float f) {
    union { float f; unsigned u; } v; v.f = f;
    unsigned r = (v.u + 0x7FFFu + ((v.u >> 16) & 1u)) >> 16;   // RNE
    return (ushort)r;
}

// packed fp32 pair -> one u32 holding 2 bf16 (RNE), low = first arg
__device__ __forceinline__ unsigned cvt_pk_bf16(float lo, float hi) {
    unsigned r;
    asm("v_cvt_pk_bf16_f32 %0, %1, %2" : "=v"(r) : "v"(lo), "v"(hi));
    return r;
}

// async global->LDS, 16B/lane. PROVEN in gemm_core; CONVICTED in attn (R4-R6
// fails, R7 bisect) — do not use outside gemm-style kernels.
__device__ __forceinline__ void gload16(const void* g, void* l) {
    __builtin_amdgcn_global_load_lds(
        (const __attribute__((address_space(1))) unsigned int*)g,
        (__attribute__((address_space(3))) unsigned int*)l,
        16, 0, 0);
}

// ---------------------------------------------------------------------------
// fp32 -> bf16 for all five tensors in one launch.
// ---------------------------------------------------------------------------
__global__ __launch_bounds__(256)
void cvt_all(const float* __restrict__ x,  const float* __restrict__ wq,
             const float* __restrict__ wk, const float* __restrict__ wv,
             const float* __restrict__ wo,
             ushort* __restrict__ xb,  ushort* __restrict__ wqb,
             ushort* __restrict__ wkb, ushort* __restrict__ wvb,
             ushort* __restrict__ wob) {
    int i = blockIdx.x * 256 + threadIdx.x;   // float4 index
    const float* src; ushort* dst; int off;
    if (i < 1048576)      { src = x;  dst = xb;  off = i; }
    else if (i < 1310720) { src = wq; dst = wqb; off = i - 1048576; }
    else if (i < 1572864) { src = wk; dst = wkb; off = i - 1310720; }
    else if (i < 1835008) { src = wv; dst = wvb; off = i - 1572864; }
    else                  { src = wo; dst = wob; off = i - 1835008; }
    const float4 v = ((const float4*)src)[off];
    ushort4 o;
    o.x = f2bf(v.x); o.y = f2bf(v.y); o.z = f2bf(v.z); o.w = f2bf(v.w);
    ((ushort4*)dst)[off] = o;
}

// ---------------------------------------------------------------------------
// 128x128x(BK=64) bf16 MFMA GEMM core (m97-style, XOR-swizzled LDS).
// PROVEN R3/R7/R8/R9. mode: 0 = plain, 1 = per-64col L2 norm (Q/K),
// 2 = V transposed per head into Vt[b,h,d,t].
// R18: mode-2 epilogue rebuilt — the old path scattered 8B uint2 stores at
// 4KB stride (each 8B in its own 64B line => ~8x write amplification on
// 8.4 MB). New: each wave transposes its 64t x 64d tile in its own dead LDS
// slice (wave-private, no barrier; 16B-chunk XOR+rotate swizzle keeps both
// phases <=2-way), then stores each d-row as a contiguous 128B run.
// ---------------------------------------------------------------------------
template<bool OUTF32>
__device__ __forceinline__
void gemm_core(const ushort* __restrict__ A, const ushort* __restrict__ W,
               const float* __restrict__ bias, void* __restrict__ out,
               int m0, int n0, int N, int K, int mode) {
    __shared__ __attribute__((aligned(16))) ushort As[128 * 64];
    __shared__ __attribute__((aligned(16))) ushort Bs[128 * 64];
    const int tid  = threadIdx.x;
    const int wave = tid >> 6, lane = tid & 63;
    const int quad = lane >> 4, l15 = lane & 15;
    const int wr = wave >> 1, wc = wave & 1;
    const int lr = lane >> 3;
    const int sc = (lane & 7) ^ lr;

    f32x4 acc[4][4] = {};
    const ushort* Ab = A + (size_t)(m0 + lr) * K + sc * 8;
    const ushort* Wb = W + (size_t)(n0 + lr) * K + sc * 8;

    for (int k0 = 0; k0 < K; k0 += 64) {
        #pragma unroll
        for (int i = 0; i < 4; i++) {
            const int rows8 = (wave * 4 + i) * 8;
            gload16(Ab + (size_t)rows8 * K + k0, &As[rows8 * 64]);
            gload16(Wb + (size_t)rows8 * K + k0, &Bs[rows8 * 64]);
        }
        __syncthreads();
        #pragma unroll
        for (int kh = 0; kh < 2; kh++) {
            short8 af[4];
            #pragma unroll
            for (int mi = 0; mi < 4; mi++) {
                const int row = wr * 64 + mi * 16 + l15;
                af[mi] = *(const short8*)&As[row * 64 + (((kh * 4 + quad) ^ (row & 7)) * 8)];
            }
            #pragma unroll
            for (int nj = 0; nj < 4; nj++) {
                const int row = wc * 64 + nj * 16 + l15;
                const short8 bf = *(const short8*)&Bs[row * 64 + (((kh * 4 + quad) ^ (row & 7)) * 8)];
                #pragma unroll
                for (int mi = 0; mi < 4; mi++)
                    acc[mi][nj] = __builtin_amdgcn_mfma_f32_16x16x32_bf16(af[mi], bf, acc[mi][nj], 0, 0, 0);
            }
        }
        __syncthreads();
    }

    if (!OUTF32 && mode == 2) {
        // Wave-private LDS slice: wave 0/1 -> As halves, wave 2/3 -> Bs halves.
        // Slice layout: [64 d][8 chunks of 8t], chunk swizzled:
        //   ch2 = ((chk ^ (d&7)) + (d>>3)) & 7
        ushort* T = (wave < 2 ? As : Bs) + (wave & 1) * 4096;
        const int t_base = m0 + wr * 64;
        const int bb = t_base >> 11, tl = t_base & 2047;
        const int hh = (n0 >> 6) + wc;
        #pragma unroll
        for (int mi = 0; mi < 4; mi++) {
            const int chk = 2 * mi + (quad >> 1);
            #pragma unroll
            for (int nj = 0; nj < 4; nj++) {
                const int dl = nj * 16 + l15;
                const int ch2 = ((chk ^ (dl & 7)) + (dl >> 3)) & 7;
                uint2 pk;
                pk.x = (unsigned)f2bf(acc[mi][nj][0]) | ((unsigned)f2bf(acc[mi][nj][1]) << 16);
                pk.y = (unsigned)f2bf(acc[mi][nj][2]) | ((unsigned)f2bf(acc[mi][nj][3]) << 16);
                // t_loc = mi*16+quad*4+r = chk*8 + (quad&1)*4 + r
                *(uint2*)&T[dl * 64 + ch2 * 8 + (quad & 1) * 4] = pk;
            }
        }
        // No barrier: each wave reads only its own slice (compiler orders
        // same-wave LDS ops via lgkmcnt).
        ushort* gp = (ushort*)out + (size_t)((bb * NH + hh) * HD + lane) * Tt + tl;
        #pragma unroll
        for (int c = 0; c < 8; c++) {
            const int ch2 = ((c ^ (lane & 7)) + (lane >> 3)) & 7;
            *(int4*)&gp[c * 8] = *(const int4*)&T[lane * 64 + ch2 * 8];
        }
        return;
    }

    #pragma unroll
    for (int mi = 0; mi < 4; mi++) {
        float inv[4] = {1.f, 1.f, 1.f, 1.f};
        if (!OUTF32 && mode == 1) {
            #pragma unroll
            for (int r = 0; r < 4; r++) {
                float ss = 0.f;
                #pragma unroll
                for (int nj = 0; nj < 4; nj++) ss += acc[mi][nj][r] * acc[mi][nj][r];
                ss += __shfl_xor(ss, 1); ss += __shfl_xor(ss, 2);
                ss += __shfl_xor(ss, 4); ss += __shfl_xor(ss, 8);
                inv[r] = 1.f / fmaxf(sqrtf(ss), EPSF);
            }
        }
        #pragma unroll
        for (int nj = 0; nj < 4; nj++)
            #pragma unroll
            for (int r = 0; r < 4; r++) {
                const int row = m0 + wr * 64 + mi * 16 + quad * 4 + r;
                const int col = n0 + wc * 64 + nj * 16 + l15;
                if (OUTF32)
                    ((float*)out)[(size_t)row * N + col] = acc[mi][nj][r] + bias[col];
                else
                    ((ushort*)out)[(size_t)row * N + col] = f2bf(acc[mi][nj][r] * inv[r]);
            }
    }
}

// Q/K: normed bf16 out; V: direct-transposed into vtb.
__global__ __launch_bounds__(256)
void qkv_gemm(const ushort* __restrict__ xb,
              const ushort* __restrict__ wq, const ushort* __restrict__ wk,
              const ushort* __restrict__ wv,
              ushort* __restrict__ qb, ushort* __restrict__ kb,
              ushort* __restrict__ vtb) {
    const int ny = blockIdx.y, sel = ny >> 3;
    const ushort* W = (sel == 0) ? wq : (sel == 1) ? wk : wv;
    ushort* out     = (sel == 0) ? qb : (sel == 1) ? kb : vtb;
    gemm_core<false>(xb, W, nullptr, out, blockIdx.x * 128, (ny & 7) * 128,
                     Dm, Dm, (sel < 2) ? 1 : 2);
}

// ---------------------------------------------------------------------------
// Output projection, 64x128 tile (grid 64x8 = 512 blocks = 2/CU).
// ---------------------------------------------------------------------------
__global__ __launch_bounds__(256)
void out_gemm(const ushort* __restrict__ A, const ushort* __restrict__ W,
              const float* __restrict__ bias, float* __restrict__ out) {
    __shared__ __attribute__((aligned(16))) ushort As[64 * 64];
    __shared__ __attribute__((aligned(16))) ushort Bs[128 * 64];
    const int tid  = threadIdx.x;
    const int wave = tid >> 6, lane = tid & 63;
    const int quad = lane >> 4, l15 = lane & 15;
    const int wm = wave & 1, wn = wave >> 1;
    const int lr = lane >> 3;
    const int sc = (lane & 7) ^ lr;
    const int m0 = blockIdx.x * 64, n0 = blockIdx.y * 128;
    const int K = Dm, N = Dm;

    f32x4 acc[2][4] = {};
    const ushort* Ab = A + (size_t)(m0 + lr) * K + sc * 8;
    const ushort* Wb = W + (size_t)(n0 + lr) * K + sc * 8;

    for (int k0 = 0; k0 < K; k0 += 64) {
        #pragma unroll
        for (int i = 0; i < 2; i++) {            // A: 8 groups, 2 per wave
            const int rows8 = (wave * 2 + i) * 8;
            gload16(Ab + (size_t)rows8 * K + k0, &As[rows8 * 64]);
        }
        #pragma unroll
        for (int i = 0; i < 4; i++) {            // B: 16 groups, 4 per wave
            const int rows8 = (wave * 4 + i) * 8;
            gload16(Wb + (size_t)rows8 * K + k0, &Bs[rows8 * 64]);
        }
        __syncthreads();
        #pragma unroll
        for (int kh = 0; kh < 2; kh++) {
            short8 af[2];
            #pragma unroll
            for (int mi = 0; mi < 2; mi++) {
                const int row = wm * 32 + mi * 16 + l15;
                af[mi] = *(const short8*)&As[row * 64 + (((kh * 4 + quad) ^ (row & 7)) * 8)];
            }
            #pragma unroll
            for (int nj = 0; nj < 4; nj++) {
                const int row = wn * 64 + nj * 16 + l15;
                const short8 bf = *(const short8*)&Bs[row * 64 + (((kh * 4 + quad) ^ (row & 7)) * 8)];
                #pragma unroll
                for (int mi = 0; mi < 2; mi++)
                    acc[mi][nj] = __builtin_amdgcn_mfma_f32_16x16x32_bf16(af[mi], bf, acc[mi][nj], 0, 0, 0);
            }
        }
        __syncthreads();
    }
    #pragma unroll
    for (int mi = 0; mi < 2; mi++)
        #pragma unroll
        for (int nj = 0; nj < 4; nj++)
            #pragma unroll
            for (int r = 0; r < 4; r++) {
                const int row = m0 + wm * 32 + mi * 16 + quad * 4 + r;
                const int col = n0 + wn * 64 + nj * 16 + l15;
                out[(size_t)row * N + col] = acc[mi][nj][r] + bias[col];
            }
}

// ---------------------------------------------------------------------------
// Fused angular attention, R18: R13's proven structure + transform (compiler
// vector code; the R16/R17 VOP3P inline-asm transform failed correctness
// twice with an unresolvable op_sel encoding model — dropped). Keeps R15's
// conflict-free 65-stride epilogue exchange (proven) and R13's 80B-pad V.
// ---------------------------------------------------------------------------
__global__ __launch_bounds__(256, 4)
void attn_kernel(const ushort* __restrict__ Qb, const ushort* __restrict__ Kb,
                 const ushort* __restrict__ Vtb, ushort* __restrict__ Ob) {
    // per team tm: buf p at tm*18432 + p*9216 : K[32][64] 4096B, V[64][40pad] 5120B
    // epilogue: Obuf float[64][65] aliases bytes 0..16640 (dead); Den at 36864.
    __shared__ __attribute__((aligned(16))) char smem[37120];
    const int tid  = threadIdx.x;
    const int wave = tid >> 6, lane = tid & 63;
    const int s = wave & 1, tm = wave >> 1;
    const int l31 = lane & 31, H = lane >> 5;
    const int t0 = blockIdx.x * 64, h = blockIdx.y, b = blockIdx.z;
    char* tbase = smem + tm * 18432;

    // Q B-frags: qf[c] holds Q[q=l31+32s][d = 16c + 8H + e]
    const size_t qrow = (size_t)(b * Tt + t0 + 32 * s + l31) * Dm + h * HD;
    short8 qf[4];
    #pragma unroll
    for (int c = 0; c < 4; c++)
        qf[c] = *(const short8*)&Qb[qrow + 16 * c + 8 * H];

    // staging geometry: team-local thread tt (0..127), 2x 16B chunks each
    const int tt = tid & 127;
    const int rk = tt >> 2, ck = (tt & 3) * 2;   // K: 32 rows x 8 chunks
    const int rv = tt >> 1, cv = (tt & 1) * 2;   // V: 64 rows x 4 chunks
    const size_t kbase  = (size_t)(b * Tt) * Dm + h * HD;
    const size_t vtbase = (size_t)((b * NH + h) * HD) * Tt;
    const ushort* kg = Kb  + kbase  + (size_t)(tm * 1024 + rk) * Dm + ck * 8;
    const ushort* vg = Vtb + vtbase + (size_t)rv * Tt + tm * 1024 + cv * 8;
    const int kw0 = rk * 128 + ((ck ^ (rk & 7)) * 16);            // bytes
    const int kw1 = rk * 128 + (((ck + 1) ^ (rk & 7)) * 16);
    const int vw0 = rv * 80 + cv * 16;                            // bytes, padded
    const int vw1 = vw0 + 16;

    f32x16 oacc[2] = {};         // O^T: oacc[dd][reg] = O[q][32dd+(reg&3)+8*(reg>>2)+4H]
    f32x2 denp = {0.f, 0.f};     // per-lane denominator partial (q lane-fixed)

    // h(t) cubic: nodes t=0,0.5,1,1.5
    const f32x2 h3 = { 0.011180f,  0.011180f};
    const f32x2 h2 = {-0.002070f, -0.002070f};
    const f32x2 h1 = { 0.040732f,  0.040732f};
    const f32x2 h0 = { 0.450158f,  0.450158f};

    // prologue: stage tile 0 into buffer 0
    short8 pk0 = *(const short8*)kg;
    short8 pk1 = *(const short8*)(kg + 8);
    short8 pv0 = *(const short8*)vg;
    short8 pv1 = *(const short8*)(vg + 8);
    *(short8*)(tbase + kw0) = pk0;
    *(short8*)(tbase + kw1) = pk1;
    *(short8*)(tbase + 4096 + vw0) = pv0;
    *(short8*)(tbase + 4096 + vw1) = pv1;
    __syncthreads();

    const ushort* kgp = kg + (size_t)32 * Dm;   // next-tile prefetch cursors
    const ushort* vgp = vg + 32;

    for (int i = 0; i < 32; i++) {
        const int p = i & 1;
        const ushort* Kp = (const ushort*)(tbase + p * 9216);
        const ushort* Vp = (const ushort*)(tbase + p * 9216 + 4096);
        if (i < 31) {   // prefetch next tile into registers
            pk0 = *(const short8*)kgp;
            pk1 = *(const short8*)(kgp + 8);
            pv0 = *(const short8*)vgp;
            pv1 = *(const short8*)(vgp + 8);
            kgp += (size_t)32 * Dm;
            vgp += 32;
        }

        // S^T = K Q^T (32x32): sf[reg] = S[q][t_k = (reg&3)+8*(reg>>2)+4H]
        f32x16 sf = {};
        #pragma unroll
        for (int c = 0; c < 4; c++) {
            const short8 kf = *(const short8*)&Kp[l31 * 64 + (((2 * c + H) ^ (l31 & 7)) * 8)];
            sf = __builtin_amdgcn_mfma_f32_32x32x16_bf16(kf, qf[c], sf, 0, 0, 0);
        }

        // sqrt-factored angular transform on 8 packed pairs (16 scores)
        f32x2 w2[8];
        #pragma unroll
        for (int ii = 0; ii < 8; ii++) {
            f32x2 tA;
            tA.x = __builtin_amdgcn_fmed3f(1.0f - sf[2 * ii],     0.001f, 1.999f);
            tA.y = __builtin_amdgcn_fmed3f(1.0f - sf[2 * ii + 1], 0.001f, 1.999f);
            f32x2 pa = __builtin_elementwise_fma(tA, h3, h2);
            pa = __builtin_elementwise_fma(pa, tA, h1);
            pa = __builtin_elementwise_fma(pa, tA, h0);
            f32x2 ra;
            ra.x = __builtin_amdgcn_sqrtf(tA.x); ra.y = __builtin_amdgcn_sqrtf(tA.y);
            const f32x2 one2 = {1.0f, 1.0f};
            f32x2 wa = __builtin_elementwise_fma(-ra, pa, one2);   // s = 1 - rt*h
            wa *= wa; wa *= wa; wa *= wa; wa *= wa;                // s^16
            denp += wa;
            w2[ii] = wa;
        }

        // Build PV B-operand W^T frags in registers.
        // P0..P3: t_k {0,1},{2,3},{8,9},{10,11} (+4H); P4..P7: +16.
        unsigned P0 = cvt_pk_bf16(w2[0].x, w2[0].y);
        unsigned P1 = cvt_pk_bf16(w2[1].x, w2[1].y);
        unsigned P2 = cvt_pk_bf16(w2[2].x, w2[2].y);
        unsigned P3 = cvt_pk_bf16(w2[3].x, w2[3].y);
        unsigned P4 = cvt_pk_bf16(w2[4].x, w2[4].y);
        unsigned P5 = cvt_pk_bf16(w2[5].x, w2[5].y);
        unsigned P6 = cvt_pk_bf16(w2[6].x, w2[6].y);
        unsigned P7 = cvt_pk_bf16(w2[7].x, w2[7].y);
        asm("v_permlane32_swap_b32 %0, %1" : "+v"(P0), "+v"(P2));
        asm("v_permlane32_swap_b32 %0, %1" : "+v"(P1), "+v"(P3));
        asm("v_permlane32_swap_b32 %0, %1" : "+v"(P4), "+v"(P6));
        asm("v_permlane32_swap_b32 %0, %1" : "+v"(P5), "+v"(P7));
        int4 bi0; bi0.x = (int)P0; bi0.y = (int)P1; bi0.z = (int)P2; bi0.w = (int)P3;
        int4 bi1; bi1.x = (int)P4; bi1.y = (int)P5; bi1.z = (int)P6; bi1.w = (int)P7;
        const short8 B0 = __builtin_bit_cast(short8, bi0);   // t_k 0..15
        const short8 B1 = __builtin_bit_cast(short8, bi1);   // t_k 16..31

        // O^T += V^T W^T : two 32-d output tiles x two k-depth-16 calls
        #pragma unroll
        for (int dd = 0; dd < 2; dd++) {
            const int vr = 32 * dd + l31;
            const short8 vf0 = *(const short8*)&Vp[vr * 40 + H * 8];
            const short8 vf1 = *(const short8*)&Vp[vr * 40 + (2 + H) * 8];
            oacc[dd] = __builtin_amdgcn_mfma_f32_32x32x16_bf16(vf0, B0, oacc[dd], 0, 0, 0);
            oacc[dd] = __builtin_amdgcn_mfma_f32_32x32x16_bf16(vf1, B1, oacc[dd], 0, 0, 0);
        }

        if (i < 31) {
            char* nb = tbase + (1 - p) * 9216;
            *(short8*)(nb + kw0) = pk0;
            *(short8*)(nb + kw1) = pk1;
            *(short8*)(nb + 4096 + vw0) = pv0;
            *(short8*)(nb + 4096 + vw1) = pv1;
        }
        __syncthreads();
    }

    // denominator: lane covers half the t_k range for its q; partner has rest
    float d = denp.x + denp.y;
    d += __shfl_xor(d, 32);

    float* Obuf = (float*)smem;             // [64 q][65 d-pad], aliases dead staging
    float* Den  = (float*)(smem + 36864);   // [64 q]
    const int ql = 32 * s + l31;

    if (tm == 1) {
        #pragma unroll
        for (int dd = 0; dd < 2; dd++)
            #pragma unroll
            for (int rg = 0; rg < 16; rg++) {
                const int dloc = 32 * dd + (rg & 3) + 8 * (rg >> 2) + 4 * H;
                Obuf[ql * 65 + dloc] = oacc[dd][rg];
            }
        if (H == 0) Den[ql] = d;
    }
    __syncthreads();

    if (tm == 0) {
        const float inv = __builtin_amdgcn_rcpf(d + Den[ql] + EPSF);
        const size_t orow = (size_t)(b * Tt + t0 + ql) * Dm + h * HD;
        #pragma unroll
        for (int dd = 0; dd < 2; dd++)
            #pragma unroll
            for (int g = 0; g < 4; g++) {
                const int dbase = 32 * dd + 8 * g + 4 * H;
                const float o0 = (oacc[dd][4 * g + 0] + Obuf[ql * 65 + dbase + 0]) * inv;
                const float o1 = (oacc[dd][4 * g + 1] + Obuf[ql * 65 + dbase + 1]) * inv;
                const float o2 = (oacc[dd][4 * g + 2] + Obuf[ql * 65 + dbase + 2]) * inv;
                const float o3 = (oacc[dd][4 * g + 3] + Obuf[ql * 65 + dbase + 3]) * inv;
                uint2 pk2;
                pk2.x = cvt_pk_bf16(o0, o1);
                pk2.y = cvt_pk_bf16(o2, o3);
                *(uint2*)&Ob[orow + dbase] = pk2;
            }
    }
}

// ---------------------------------------------------------------------------
extern "C" void kernel_launch(void* const* d_in, const int* in_sizes, int n_in,
                              void* d_out, int out_size, void* d_ws, size_t ws_size,
                              hipStream_t stream) {
    const float* x  = (const float*)d_in[0];
    const float* Wq = (const float*)d_in[1];
    const float* Wk = (const float*)d_in[2];
    const float* Wv = (const float*)d_in[3];
    const float* Wo = (const float*)d_in[4];
    const float* bo = (const float*)d_in[5];
    float* out = (float*)d_out;

    ushort* ws = (ushort*)d_ws;
    const size_t M1 = 1u << 20;
    ushort* xb  = ws;
    ushort* wqb = ws + 4 * M1;
    ushort* wkb = ws + 5 * M1;
    ushort* wvb = ws + 6 * M1;
    ushort* wob = ws + 7 * M1;
    ushort* qb  = ws + 8 * M1;
    ushort* kb  = ws + 12 * M1;
    ushort* vtb = ws + 16 * M1;
    ushort* aob = ws + 20 * M1;

    cvt_all<<<8192, 256, 0, stream>>>(x, Wq, Wk, Wv, Wo, xb, wqb, wkb, wvb, wob);
    qkv_gemm<<<dim3(MTOT / 128, 24), 256, 0, stream>>>(xb, wqb, wkb, wvb, qb, kb, vtb);
    attn_kernel<<<dim3(Tt / 64, NH, Bb), 256, 0, stream>>>(qb, kb, vtb, aob);
    out_gemm<<<dim3(MTOT / 64, Dm / 128), 256, 0, stream>>>(aob, wob, bo, out);
}

// Round 10
// 214.891 us; speedup vs baseline: 1.0084x; 1.0084x over previous
//
#include <hip/hip_runtime.h>
#include <math.h>

// Problem constants
constexpr int Dm   = 1024;
constexpr int NH   = 16;
constexpr int HD   = 64;
constexpr int Bb   = 2;
constexpr int Tt   = 2048;
constexpr int MTOT = Bb * Tt;   // 4096
#define EPSF 1e-6f

typedef __attribute__((ext_vector_type(8))) short short8;   // 8 x bf16
typedef __attribute__((ext_vector_type(4))) float f32x4;    // MFMA acc (16x16)
typedef __attribute__((ext_vector_type(16))) float f32x16;  // MFMA acc (32x32)
typedef __attribute__((ext_vector_type(2))) float f32x2;    // packed fp32 pair

__device__ __forceinline__ ushort f2bf(float f) {
    union { float f; unsigned u; } v; v.f = f;
    unsigned r = (v.u + 0x7FFFu + ((v.u >> 16) & 1u)) >> 16;   // RNE
    return (ushort)r;
}

// packed fp32 pair -> one u32 holding 2 bf16 (RNE), low = first arg
__device__ __forceinline__ unsigned cvt_pk_bf16(float lo, float hi) {
    unsigned r;
    asm("v_cvt_pk_bf16_f32 %0, %1, %2" : "=v"(r) : "v"(lo), "v"(hi));
    return r;
}

// async global->LDS, 16B/lane. PROVEN in gemm_core; CONVICTED in attn (R4-R6
// fails, R7 bisect) — do not use outside gemm-style kernels.
__device__ __forceinline__ void gload16(const void* g, void* l) {
    __builtin_amdgcn_global_load_lds(
        (const __attribute__((address_space(1))) unsigned int*)g,
        (__attribute__((address_space(3))) unsigned int*)l,
        16, 0, 0);
}

// ---------------------------------------------------------------------------
// fp32 -> bf16 for all five tensors in one launch.
// ---------------------------------------------------------------------------
__global__ __launch_bounds__(256)
void cvt_all(const float* __restrict__ x,  const float* __restrict__ wq,
             const float* __restrict__ wk, const float* __restrict__ wv,
             const float* __restrict__ wo,
             ushort* __restrict__ xb,  ushort* __restrict__ wqb,
             ushort* __restrict__ wkb, ushort* __restrict__ wvb,
             ushort* __restrict__ wob) {
    int i = blockIdx.x * 256 + threadIdx.x;   // float4 index
    const float* src; ushort* dst; int off;
    if (i < 1048576)      { src = x;  dst = xb;  off = i; }
    else if (i < 1310720) { src = wq; dst = wqb; off = i - 1048576; }
    else if (i < 1572864) { src = wk; dst = wkb; off = i - 1310720; }
    else if (i < 1835008) { src = wv; dst = wvb; off = i - 1572864; }
    else                  { src = wo; dst = wob; off = i - 1835008; }
    const float4 v = ((const float4*)src)[off];
    ushort4 o;
    o.x = f2bf(v.x); o.y = f2bf(v.y); o.z = f2bf(v.z); o.w = f2bf(v.w);
    ((ushort4*)dst)[off] = o;
}

// ---------------------------------------------------------------------------
// 128x128 bf16 MFMA GEMM core, R19: BK=32 double-buffered prefetch pipeline.
// R18 analysis: qkv+out imply ~110us vs ~50us roofline; the old BK=64 loop was
// stage -> barrier(vmcnt0 drain, ZERO compute in flight) -> compute -> barrier,
// exposing full load latency every K-iter. New: 2 buffers of [128][32] (same
// 32KB LDS), issue next tile's gload16s BEFORE computing current, one barrier
// per iter (drains loads that had a full compute phase to land). Same totals:
// 128 gload16, 256 ds_read_b128, 512 MFMA, 32 barriers per block.
// Staging swizzle (64B rows, 4 chunks): lane fetches global chunk
// (lane&3)^((arow>>1)&3) so linear gload16 dest holds swizzled data; read slot
// quad^((l15>>1)&3) — both patterns 8 distinct 16B slots per phase.
// mode: 0 plain, 1 per-64col L2 norm (Q/K), 2 V transposed (R18 LDS epilogue).
// ---------------------------------------------------------------------------
template<bool OUTF32>
__device__ __forceinline__
void gemm_core(const ushort* __restrict__ A, const ushort* __restrict__ W,
               const float* __restrict__ bias, void* __restrict__ out,
               int m0, int n0, int N, int K, int mode) {
    __shared__ __attribute__((aligned(16))) ushort As[2 * 128 * 32];
    __shared__ __attribute__((aligned(16))) ushort Bs[2 * 128 * 32];
    const int tid  = threadIdx.x;
    const int wave = tid >> 6, lane = tid & 63;
    const int quad = lane >> 4, l15 = lane & 15;
    const int wr = wave >> 1, wc = wave & 1;

    // staging geometry: one gload16 call = 64 lanes = 16 rows x 4 chunks(16B)
    const int arow = lane >> 2;                          // row within call
    const int acs  = (lane & 3) ^ ((arow >> 1) & 3);     // swizzled global chunk
    const ushort* Ag = A + (size_t)(m0 + arow) * K + acs * 8;
    const ushort* Wg = W + (size_t)(n0 + arow) * K + acs * 8;
    const int pr = (l15 >> 1) & 3;                       // read-side swizzle

    f32x4 acc[4][4] = {};

    // prologue: stage tile 0 into buffer 0 (2 calls per array per wave)
    #pragma unroll
    for (int j = 0; j < 2; j++) {
        const int r16 = wave * 2 + j;
        gload16(Ag + (size_t)(r16 * 16) * K, &As[r16 * 512]);
        gload16(Wg + (size_t)(r16 * 16) * K, &Bs[r16 * 512]);
    }
    __syncthreads();

    for (int it = 0; it < 32; ++it) {
        const int cur = (it & 1) * 4096;
        if (it < 31) {   // issue next tile's loads; they fly during compute
            const int nxt = 4096 - cur;
            const size_t k0 = (size_t)(it + 1) * 32;
            #pragma unroll
            for (int j = 0; j < 2; j++) {
                const int r16 = wave * 2 + j;
                gload16(Ag + (size_t)(r16 * 16) * K + k0, &As[nxt + r16 * 512]);
                gload16(Wg + (size_t)(r16 * 16) * K + k0, &Bs[nxt + r16 * 512]);
            }
        }
        short8 af[4];
        #pragma unroll
        for (int mi = 0; mi < 4; mi++) {
            const int row = wr * 64 + mi * 16 + l15;
            af[mi] = *(const short8*)&As[cur + row * 32 + ((quad ^ pr) * 8)];
        }
        #pragma unroll
        for (int nj = 0; nj < 4; nj++) {
            const int row = wc * 64 + nj * 16 + l15;
            const short8 bf = *(const short8*)&Bs[cur + row * 32 + ((quad ^ pr) * 8)];
            #pragma unroll
            for (int mi = 0; mi < 4; mi++)
                acc[mi][nj] = __builtin_amdgcn_mfma_f32_16x16x32_bf16(af[mi], bf, acc[mi][nj], 0, 0, 0);
        }
        __syncthreads();   // reads of cur done everywhere; prefetch landed
    }

    if (!OUTF32 && mode == 2) {
        // Wave-private LDS transpose slice (R18): wave 0/1 -> As halves,
        // wave 2/3 -> Bs halves (arrays are 8192 ushorts each, now dead).
        ushort* T = (wave < 2 ? As : Bs) + (wave & 1) * 4096;
        const int t_base = m0 + wr * 64;
        const int bb = t_base >> 11, tl = t_base & 2047;
        const int hh = (n0 >> 6) + wc;
        #pragma unroll
        for (int mi = 0; mi < 4; mi++) {
            const int chk = 2 * mi + (quad >> 1);
            #pragma unroll
            for (int nj = 0; nj < 4; nj++) {
                const int dl = nj * 16 + l15;
                const int ch2 = ((chk ^ (dl & 7)) + (dl >> 3)) & 7;
                uint2 pk;
                pk.x = (unsigned)f2bf(acc[mi][nj][0]) | ((unsigned)f2bf(acc[mi][nj][1]) << 16);
                pk.y = (unsigned)f2bf(acc[mi][nj][2]) | ((unsigned)f2bf(acc[mi][nj][3]) << 16);
                *(uint2*)&T[dl * 64 + ch2 * 8 + (quad & 1) * 4] = pk;
            }
        }
        ushort* gp = (ushort*)out + (size_t)((bb * NH + hh) * HD + lane) * Tt + tl;
        #pragma unroll
        for (int c = 0; c < 8; c++) {
            const int ch2 = ((c ^ (lane & 7)) + (lane >> 3)) & 7;
            *(int4*)&gp[c * 8] = *(const int4*)&T[lane * 64 + ch2 * 8];
        }
        return;
    }

    #pragma unroll
    for (int mi = 0; mi < 4; mi++) {
        float inv[4] = {1.f, 1.f, 1.f, 1.f};
        if (!OUTF32 && mode == 1) {
            #pragma unroll
            for (int r = 0; r < 4; r++) {
                float ss = 0.f;
                #pragma unroll
                for (int nj = 0; nj < 4; nj++) ss += acc[mi][nj][r] * acc[mi][nj][r];
                ss += __shfl_xor(ss, 1); ss += __shfl_xor(ss, 2);
                ss += __shfl_xor(ss, 4); ss += __shfl_xor(ss, 8);
                inv[r] = 1.f / fmaxf(sqrtf(ss), EPSF);
            }
        }
        #pragma unroll
        for (int nj = 0; nj < 4; nj++)
            #pragma unroll
            for (int r = 0; r < 4; r++) {
                const int row = m0 + wr * 64 + mi * 16 + quad * 4 + r;
                const int col = n0 + wc * 64 + nj * 16 + l15;
                if (OUTF32)
                    ((float*)out)[(size_t)row * N + col] = acc[mi][nj][r] + bias[col];
                else
                    ((ushort*)out)[(size_t)row * N + col] = f2bf(acc[mi][nj][r] * inv[r]);
            }
    }
}

// Q/K: normed bf16 out; V: direct-transposed into vtb.
__global__ __launch_bounds__(256)
void qkv_gemm(const ushort* __restrict__ xb,
              const ushort* __restrict__ wq, const ushort* __restrict__ wk,
              const ushort* __restrict__ wv,
              ushort* __restrict__ qb, ushort* __restrict__ kb,
              ushort* __restrict__ vtb) {
    const int ny = blockIdx.y, sel = ny >> 3;
    const ushort* W = (sel == 0) ? wq : (sel == 1) ? wk : wv;
    ushort* out     = (sel == 0) ? qb : (sel == 1) ? kb : vtb;
    gemm_core<false>(xb, W, nullptr, out, blockIdx.x * 128, (ny & 7) * 128,
                     Dm, Dm, (sel < 2) ? 1 : 2);
}

// ---------------------------------------------------------------------------
// Output projection, 64x128 tile (512 blocks = 2/CU), R19: same BK=32
// double-buffered prefetch pipeline as gemm_core. LDS 24KB (unchanged).
// ---------------------------------------------------------------------------
__global__ __launch_bounds__(256)
void out_gemm(const ushort* __restrict__ A, const ushort* __restrict__ W,
              const float* __restrict__ bias, float* __restrict__ out) {
    __shared__ __attribute__((aligned(16))) ushort As[2 * 64 * 32];
    __shared__ __attribute__((aligned(16))) ushort Bs[2 * 128 * 32];
    const int tid  = threadIdx.x;
    const int wave = tid >> 6, lane = tid & 63;
    const int quad = lane >> 4, l15 = lane & 15;
    const int wm = wave & 1, wn = wave >> 1;
    const int m0 = blockIdx.x * 64, n0 = blockIdx.y * 128;
    const int K = Dm, N = Dm;

    const int arow = lane >> 2;
    const int acs  = (lane & 3) ^ ((arow >> 1) & 3);
    const ushort* Ag = A + (size_t)(m0 + arow) * K + acs * 8;
    const ushort* Wg = W + (size_t)(n0 + arow) * K + acs * 8;
    const int pr = (l15 >> 1) & 3;

    f32x4 acc[2][4] = {};

    // prologue: A = 4 calls (1/wave, 16 rows each), B = 8 calls (2/wave)
    gload16(Ag + (size_t)(wave * 16) * K, &As[wave * 512]);
    #pragma unroll
    for (int j = 0; j < 2; j++) {
        const int r16 = wave * 2 + j;
        gload16(Wg + (size_t)(r16 * 16) * K, &Bs[r16 * 512]);
    }
    __syncthreads();

    for (int it = 0; it < 32; ++it) {
        const int curA = (it & 1) * 2048, curB = (it & 1) * 4096;
        if (it < 31) {
            const int nxtA = 2048 - curA, nxtB = 4096 - curB;
            const size_t k0 = (size_t)(it + 1) * 32;
            gload16(Ag + (size_t)(wave * 16) * K + k0, &As[nxtA + wave * 512]);
            #pragma unroll
            for (int j = 0; j < 2; j++) {
                const int r16 = wave * 2 + j;
                gload16(Wg + (size_t)(r16 * 16) * K + k0, &Bs[nxtB + r16 * 512]);
            }
        }
        short8 af[2];
        #pragma unroll
        for (int mi = 0; mi < 2; mi++) {
            const int row = wm * 32 + mi * 16 + l15;
            af[mi] = *(const short8*)&As[curA + row * 32 + ((quad ^ pr) * 8)];
        }
        #pragma unroll
        for (int nj = 0; nj < 4; nj++) {
            const int row = wn * 64 + nj * 16 + l15;
            const short8 bf = *(const short8*)&Bs[curB + row * 32 + ((quad ^ pr) * 8)];
            #pragma unroll
            for (int mi = 0; mi < 2; mi++)
                acc[mi][nj] = __builtin_amdgcn_mfma_f32_16x16x32_bf16(af[mi], bf, acc[mi][nj], 0, 0, 0);
        }
        __syncthreads();
    }
    #pragma unroll
    for (int mi = 0; mi < 2; mi++)
        #pragma unroll
        for (int nj = 0; nj < 4; nj++)
            #pragma unroll
            for (int r = 0; r < 4; r++) {
                const int row = m0 + wm * 32 + mi * 16 + quad * 4 + r;
                const int col = n0 + wn * 64 + nj * 16 + l15;
                out[(size_t)row * N + col] = acc[mi][nj][r] + bias[col];
            }
}

// ---------------------------------------------------------------------------
// Fused angular attention, R18 (unchanged, proven 77.0us): R13 structure +
// transform, R13 80B-pad V, R15 65-stride epilogue exchange.
// ---------------------------------------------------------------------------
__global__ __launch_bounds__(256, 4)
void attn_kernel(const ushort* __restrict__ Qb, const ushort* __restrict__ Kb,
                 const ushort* __restrict__ Vtb, ushort* __restrict__ Ob) {
    // per team tm: buf p at tm*18432 + p*9216 : K[32][64] 4096B, V[64][40pad] 5120B
    // epilogue: Obuf float[64][65] aliases bytes 0..16640 (dead); Den at 36864.
    __shared__ __attribute__((aligned(16))) char smem[37120];
    const int tid  = threadIdx.x;
    const int wave = tid >> 6, lane = tid & 63;
    const int s = wave & 1, tm = wave >> 1;
    const int l31 = lane & 31, H = lane >> 5;
    const int t0 = blockIdx.x * 64, h = blockIdx.y, b = blockIdx.z;
    char* tbase = smem + tm * 18432;

    // Q B-frags: qf[c] holds Q[q=l31+32s][d = 16c + 8H + e]
    const size_t qrow = (size_t)(b * Tt + t0 + 32 * s + l31) * Dm + h * HD;
    short8 qf[4];
    #pragma unroll
    for (int c = 0; c < 4; c++)
        qf[c] = *(const short8*)&Qb[qrow + 16 * c + 8 * H];

    // staging geometry: team-local thread tt (0..127), 2x 16B chunks each
    const int tt = tid & 127;
    const int rk = tt >> 2, ck = (tt & 3) * 2;   // K: 32 rows x 8 chunks
    const int rv = tt >> 1, cv = (tt & 1) * 2;   // V: 64 rows x 4 chunks
    const size_t kbase  = (size_t)(b * Tt) * Dm + h * HD;
    const size_t vtbase = (size_t)((b * NH + h) * HD) * Tt;
    const ushort* kg = Kb  + kbase  + (size_t)(tm * 1024 + rk) * Dm + ck * 8;
    const ushort* vg = Vtb + vtbase + (size_t)rv * Tt + tm * 1024 + cv * 8;
    const int kw0 = rk * 128 + ((ck ^ (rk & 7)) * 16);            // bytes
    const int kw1 = rk * 128 + (((ck + 1) ^ (rk & 7)) * 16);
    const int vw0 = rv * 80 + cv * 16;                            // bytes, padded
    const int vw1 = vw0 + 16;

    f32x16 oacc[2] = {};         // O^T: oacc[dd][reg] = O[q][32dd+(reg&3)+8*(reg>>2)+4H]
    f32x2 denp = {0.f, 0.f};     // per-lane denominator partial (q lane-fixed)

    // h(t) cubic: nodes t=0,0.5,1,1.5
    const f32x2 h3 = { 0.011180f,  0.011180f};
    const f32x2 h2 = {-0.002070f, -0.002070f};
    const f32x2 h1 = { 0.040732f,  0.040732f};
    const f32x2 h0 = { 0.450158f,  0.450158f};

    // prologue: stage tile 0 into buffer 0
    short8 pk0 = *(const short8*)kg;
    short8 pk1 = *(const short8*)(kg + 8);
    short8 pv0 = *(const short8*)vg;
    short8 pv1 = *(const short8*)(vg + 8);
    *(short8*)(tbase + kw0) = pk0;
    *(short8*)(tbase + kw1) = pk1;
    *(short8*)(tbase + 4096 + vw0) = pv0;
    *(short8*)(tbase + 4096 + vw1) = pv1;
    __syncthreads();

    const ushort* kgp = kg + (size_t)32 * Dm;   // next-tile prefetch cursors
    const ushort* vgp = vg + 32;

    for (int i = 0; i < 32; i++) {
        const int p = i & 1;
        const ushort* Kp = (const ushort*)(tbase + p * 9216);
        const ushort* Vp = (const ushort*)(tbase + p * 9216 + 4096);
        if (i < 31) {   // prefetch next tile into registers
            pk0 = *(const short8*)kgp;
            pk1 = *(const short8*)(kgp + 8);
            pv0 = *(const short8*)vgp;
            pv1 = *(const short8*)(vgp + 8);
            kgp += (size_t)32 * Dm;
            vgp += 32;
        }

        // S^T = K Q^T (32x32): sf[reg] = S[q][t_k = (reg&3)+8*(reg>>2)+4H]
        f32x16 sf = {};
        #pragma unroll
        for (int c = 0; c < 4; c++) {
            const short8 kf = *(const short8*)&Kp[l31 * 64 + (((2 * c + H) ^ (l31 & 7)) * 8)];
            sf = __builtin_amdgcn_mfma_f32_32x32x16_bf16(kf, qf[c], sf, 0, 0, 0);
        }

        // sqrt-factored angular transform on 8 packed pairs (16 scores)
        f32x2 w2[8];
        #pragma unroll
        for (int ii = 0; ii < 8; ii++) {
            f32x2 tA;
            tA.x = __builtin_amdgcn_fmed3f(1.0f - sf[2 * ii],     0.001f, 1.999f);
            tA.y = __builtin_amdgcn_fmed3f(1.0f - sf[2 * ii + 1], 0.001f, 1.999f);
            f32x2 pa = __builtin_elementwise_fma(tA, h3, h2);
            pa = __builtin_elementwise_fma(pa, tA, h1);
            pa = __builtin_elementwise_fma(pa, tA, h0);
            f32x2 ra;
            ra.x = __builtin_amdgcn_sqrtf(tA.x); ra.y = __builtin_amdgcn_sqrtf(tA.y);
            const f32x2 one2 = {1.0f, 1.0f};
            f32x2 wa = __builtin_elementwise_fma(-ra, pa, one2);   // s = 1 - rt*h
            wa *= wa; wa *= wa; wa *= wa; wa *= wa;                // s^16
            denp += wa;
            w2[ii] = wa;
        }

        // Build PV B-operand W^T frags in registers.
        // P0..P3: t_k {0,1},{2,3},{8,9},{10,11} (+4H); P4..P7: +16.
        unsigned P0 = cvt_pk_bf16(w2[0].x, w2[0].y);
        unsigned P1 = cvt_pk_bf16(w2[1].x, w2[1].y);
        unsigned P2 = cvt_pk_bf16(w2[2].x, w2[2].y);
        unsigned P3 = cvt_pk_bf16(w2[3].x, w2[3].y);
        unsigned P4 = cvt_pk_bf16(w2[4].x, w2[4].y);
        unsigned P5 = cvt_pk_bf16(w2[5].x, w2[5].y);
        unsigned P6 = cvt_pk_bf16(w2[6].x, w2[6].y);
        unsigned P7 = cvt_pk_bf16(w2[7].x, w2[7].y);
        asm("v_permlane32_swap_b32 %0, %1" : "+v"(P0), "+v"(P2));
        asm("v_permlane32_swap_b32 %0, %1" : "+v"(P1), "+v"(P3));
        asm("v_permlane32_swap_b32 %0, %1" : "+v"(P4), "+v"(P6));
        asm("v_permlane32_swap_b32 %0, %1" : "+v"(P5), "+v"(P7));
        int4 bi0; bi0.x = (int)P0; bi0.y = (int)P1; bi0.z = (int)P2; bi0.w = (int)P3;
        int4 bi1; bi1.x = (int)P4; bi1.y = (int)P5; bi1.z = (int)P6; bi1.w = (int)P7;
        const short8 B0 = __builtin_bit_cast(short8, bi0);   // t_k 0..15
        const short8 B1 = __builtin_bit_cast(short8, bi1);   // t_k 16..31

        // O^T += V^T W^T : two 32-d output tiles x two k-depth-16 calls
        #pragma unroll
        for (int dd = 0; dd < 2; dd++) {
            const int vr = 32 * dd + l31;
            const short8 vf0 = *(const short8*)&Vp[vr * 40 + H * 8];
            const short8 vf1 = *(const short8*)&Vp[vr * 40 + (2 + H) * 8];
            oacc[dd] = __builtin_amdgcn_mfma_f32_32x32x16_bf16(vf0, B0, oacc[dd], 0, 0, 0);
            oacc[dd] = __builtin_amdgcn_mfma_f32_32x32x16_bf16(vf1, B1, oacc[dd], 0, 0, 0);
        }

        if (i < 31) {
            char* nb = tbase + (1 - p) * 9216;
            *(short8*)(nb + kw0) = pk0;
            *(short8*)(nb + kw1) = pk1;
            *(short8*)(nb + 4096 + vw0) = pv0;
            *(short8*)(nb + 4096 + vw1) = pv1;
        }
        __syncthreads();
    }

    // denominator: lane covers half the t_k range for its q; partner has rest
    float d = denp.x + denp.y;
    d += __shfl_xor(d, 32);

    float* Obuf = (float*)smem;             // [64 q][65 d-pad], aliases dead staging
    float* Den  = (float*)(smem + 36864);   // [64 q]
    const int ql = 32 * s + l31;

    if (tm == 1) {
        #pragma unroll
        for (int dd = 0; dd < 2; dd++)
            #pragma unroll
            for (int rg = 0; rg < 16; rg++) {
                const int dloc = 32 * dd + (rg & 3) + 8 * (rg >> 2) + 4 * H;
                Obuf[ql * 65 + dloc] = oacc[dd][rg];
            }
        if (H == 0) Den[ql] = d;
    }
    __syncthreads();

    if (tm == 0) {
        const float inv = __builtin_amdgcn_rcpf(d + Den[ql] + EPSF);
        const size_t orow = (size_t)(b * Tt + t0 + ql) * Dm + h * HD;
        #pragma unroll
        for (int dd = 0; dd < 2; dd++)
            #pragma unroll
            for (int g = 0; g < 4; g++) {
                const int dbase = 32 * dd + 8 * g + 4 * H;
                const float o0 = (oacc[dd][4 * g + 0] + Obuf[ql * 65 + dbase + 0]) * inv;
                const float o1 = (oacc[dd][4 * g + 1] + Obuf[ql * 65 + dbase + 1]) * inv;
                const float o2 = (oacc[dd][4 * g + 2] + Obuf[ql * 65 + dbase + 2]) * inv;
                const float o3 = (oacc[dd][4 * g + 3] + Obuf[ql * 65 + dbase + 3]) * inv;
                uint2 pk2;
                pk2.x = cvt_pk_bf16(o0, o1);
                pk2.y = cvt_pk_bf16(o2, o3);
                *(uint2*)&Ob[orow + dbase] = pk2;
            }
    }
}

// ---------------------------------------------------------------------------
extern "C" void kernel_launch(void* const* d_in, const int* in_sizes, int n_in,
                              void* d_out, int out_size, void* d_ws, size_t ws_size,
                              hipStream_t stream) {
    const float* x  = (const float*)d_in[0];
    const float* Wq = (const float*)d_in[1];
    const float* Wk = (const float*)d_in[2];
    const float* Wv = (const float*)d_in[3];
    const float* Wo = (const float*)d_in[4];
    const float* bo = (const float*)d_in[5];
    float* out = (float*)d_out;

    ushort* ws = (ushort*)d_ws;
    const size_t M1 = 1u << 20;
    ushort* xb  = ws;
    ushort* wqb = ws + 4 * M1;
    ushort* wkb = ws + 5 * M1;
    ushort* wvb = ws + 6 * M1;
    ushort* wob = ws + 7 * M1;
    ushort* qb  = ws + 8 * M1;
    ushort* kb  = ws + 12 * M1;
    ushort* vtb = ws + 16 * M1;
    ushort* aob = ws + 20 * M1;

    cvt_all<<<8192, 256, 0, stream>>>(x, Wq, Wk, Wv, Wo, xb, wqb, wkb, wvb, wob);
    qkv_gemm<<<dim3(MTOT / 128, 24), 256, 0, stream>>>(xb, wqb, wkb, wvb, qb, kb, vtb);
    attn_kernel<<<dim3(Tt / 64, NH, Bb), 256, 0, stream>>>(qb, kb, vtb, aob);
    out_gemm<<<dim3(MTOT / 64, Dm / 128), 256, 0, stream>>>(aob, wob, bo, out);
}